// Round 2
// baseline (251.020 us; speedup 1.0000x reference)
//
#include <hip/hip_runtime.h>
#include <cmath>

namespace {
constexpr int BN = 1024;
constexpr int NC = 96;
constexpr int MT = 256;
constexpr int UL = 40;
constexpr int LS = 81;     // 2*UL+1 states
constexpr int PAIRS = 41;  // pairs per row (lane i -> states 2i, 2i+1)
constexpr int ROWS = 128;  // buffered rows (max partner row = floor(T/2)-1 <= 127)

template <int CTRL>
__device__ __forceinline__ float dppf(float v) {
  return __builtin_bit_cast(
      float, __builtin_amdgcn_update_dpp(0, __builtin_bit_cast(int, v), CTRL,
                                         0xf, 0xf, true));
}
__device__ __forceinline__ float rl63(float x) {
  return __builtin_bit_cast(
      float, __builtin_amdgcn_readlane(__builtin_bit_cast(int, x), 63));
}
__device__ __forceinline__ float wave_sum(float x) {
  x += dppf<0x111>(x);
  x += dppf<0x112>(x);
  x += dppf<0x114>(x);
  x += dppf<0x118>(x);
  x += dppf<0x142>(x);
  x += dppf<0x143>(x);
  return rl63(x);
}
// lane i <- lane i-1 (lane 0 <- 0)
__device__ __forceinline__ float wave_shr1(float v) { return dppf<0x138>(v); }
__device__ __forceinline__ float fast_rcp(float x) {
  return __builtin_amdgcn_rcpf(x);
}
__device__ __forceinline__ unsigned packu(float a, float b) {
  unsigned ua = __builtin_bit_cast(unsigned, a) >> 16;
  unsigned ub = __builtin_bit_cast(unsigned, b) & 0xffff0000u;
  return ua | ub;
}
__device__ __forceinline__ float bf_lo(unsigned u) {
  return __builtin_bit_cast(float, u << 16);
}
__device__ __forceinline__ float bf_hi(unsigned u) {
  return __builtin_bit_cast(float, u & 0xffff0000u);
}

constexpr float FQ = 1e8f;      // nominal row scale (shock headroom)
constexpr float SEPS = 1e-30f;  // rcp-input floor (NaN-proof)

// Fully fused CTC, ONE WAVE PER ITEM: lanes run BOTH the alpha chain (A) and
// the beta chain (B) simultaneously (2x ILP on the serial recurrences; their
// latency stalls overlap). No barriers anywhere: rows are published to LDS
// (normalized, bf16x2, reference-aligned columns; beta pair-reversed+shifted)
// and read back by the SAME wave. Every loss term t is computed exactly once
// at step k = max(t, T-1-t): at the end of block t0 (after publish), for each
// k >= kstart = T>>1 we form
//   term t=k      : own alpha row k (regs, /fsA) . beta row T-1-k (LDS)
//   term t=T-1-k  : own beta row k (regs, /fsB)  . alpha row T-1-k (LDS)
// with dedupe when 2k == T-1 (odd T middle). Partner rows T-1-k <= floor(T/2)-1
// <= 127 are always already published (same-wave visibility, rows <= t0+7).
__global__ __launch_bounds__(64) void ctc_fused_kernel(
    const float* __restrict__ gout, const int* __restrict__ glabel,
    const int* __restrict__ gw, float* __restrict__ loss_out) {
  __shared__ unsigned sA[ROWS * PAIRS];  // alpha rows, reference columns
  __shared__ unsigned sB[ROWS * PAIRS];  // beta rows, reference columns
  const int b = blockIdx.x;
  const int i = threadIdx.x;  // 0..63
  const float* P = gout + (size_t)b * (NC * MT);  // P[c*MT + t]
  const int* lab = glabel + b * UL;
  const int T = gw[b] >> 2;  // [128,256]
  const int kstart = T >> 1;

  const int s0 = 2 * i, s1 = s0 + 1;
  const float h0f = (i <= 40) ? 1.f : 0.f;
  const float h1f = (i <= 39) ? 1.f : 0.f;
  const int iw = (i <= 40) ? i : 40;
  const bool act = (i <= 40);

  // ---- alpha (A) setup ----
  const int li = (i < UL) ? lab[i] : 0;
  const int lm = (i >= 1 && i < UL) ? lab[i - 1] : 0;
  const float* pBA = P;
  const float* pLA = P + (size_t)li * MT;
  const float mskA = (i >= 1 && i <= 39 && li != lm) ? 1.f : 0.f;
  const int colA = iw;  // alpha publishes straight
  // ---- beta (B) setup: class-flipped probs, reversed labels ----
  const int rli = (i < UL) ? lab[UL - 1 - i] : 0;
  const int rlm = (i >= 1 && i < UL) ? lab[UL - i] : 0;
  const float* pBB = P + (size_t)(NC - 1) * MT;
  const float* pLB = P + (size_t)(NC - 1 - rli) * MT;
  const float mskB = (i >= 1 && i <= 39 && rli != rlm) ? 1.f : 0.f;
  const int colB = 40 - iw;  // beta publishes pair-reversed -> reference cols

  // ---- prob pipeline (per chain): current block unpacked, next in flight ----
  float pbvA[8], plvA[8], pbvB[8], plvB[8];
  float4 LAA = *(const float4*)(pBA + 0), LBA = *(const float4*)(pBA + 4);
  float4 MAA = *(const float4*)(pLA + 0), MBA = *(const float4*)(pLA + 4);
  float4 LAB = *(const float4*)(pBB + 0), LBB = *(const float4*)(pBB + 4);
  float4 MAB = *(const float4*)(pLB + 0), MBB = *(const float4*)(pLB + 4);
  pbvA[0] = LAA.x; pbvA[1] = LAA.y; pbvA[2] = LAA.z; pbvA[3] = LAA.w;
  pbvA[4] = LBA.x; pbvA[5] = LBA.y; pbvA[6] = LBA.z; pbvA[7] = LBA.w;
  plvA[0] = MAA.x; plvA[1] = MAA.y; plvA[2] = MAA.z; plvA[3] = MAA.w;
  plvA[4] = MBA.x; plvA[5] = MBA.y; plvA[6] = MBA.z; plvA[7] = MBA.w;
  pbvB[0] = LAB.x; pbvB[1] = LAB.y; pbvB[2] = LAB.z; pbvB[3] = LAB.w;
  pbvB[4] = LBB.x; pbvB[5] = LBB.y; pbvB[6] = LBB.z; pbvB[7] = LBB.w;
  plvB[0] = MAB.x; plvB[1] = MAB.y; plvB[2] = MAB.z; plvB[3] = MAB.w;
  plvB[4] = MBB.x; plvB[5] = MBB.y; plvB[6] = MBB.z; plvB[7] = MBB.w;
  LAA = *(const float4*)(pBA + 8); LBA = *(const float4*)(pBA + 12);
  MAA = *(const float4*)(pLA + 8); MBA = *(const float4*)(pLA + 12);
  LAB = *(const float4*)(pBB + 8); LBB = *(const float4*)(pBB + 12);
  MAB = *(const float4*)(pLB + 8); MBB = *(const float4*)(pLB + 12);

  // ---- t = 0 (both chains) ----
  float v0A = (i == 0) ? pbvA[0] : 0.f;
  float v1A = (i == 0) ? plvA[0] : 0.f;
  float v0B = (i == 0) ? pbvB[0] : 0.f;
  float v1B = (i == 0) ? plvB[0] : 0.f;
  float ssA = wave_sum(v0A + v1A);
  float ssB = wave_sum(v0B + v1B);
  float r0qA = FQ * fast_rcp(fmaxf(ssA, SEPS));
  float r1qA = FQ * fast_rcp(fmaxf(ssA * r0qA, SEPS));
  float r2qA = FQ * fast_rcp(fmaxf(ssA * r0qA * r1qA, SEPS));
  float r0qB = FQ * fast_rcp(fmaxf(ssB, SEPS));
  float r1qB = FQ * fast_rcp(fmaxf(ssB * r0qB, SEPS));
  float r2qB = FQ * fast_rcp(fmaxf(ssB * r0qB * r1qB, SEPS));

  float f0A[8], f1A[8], fsA[8];  // alpha: x-values (a/p) + raw row sums
  float f0B[8], f1B[8], fsB[8];  // beta: raw values + raw row sums
  fsA[0] = ssA;
  f0A[0] = (i == 0) ? 1.f : 0.f;  // x = a_raw/p at t=0
  f1A[0] = f0A[0];
  fsB[0] = ssB;
  f0B[0] = v0B;
  f1B[0] = 0.f;  // overwritten by step k=1's pm1
  float acc = 0.f;  // sum of log(lh_t); wave-uniform

#define CTC_STEP(S, BETA, T_, K_)                                     \
  {                                                                   \
    float pm1 = wave_shr1(v1##S);                                     \
    if ((BETA) && (K_) >= 1) f1##S[(K_)-1] = pm1;                     \
    const float rh0 = r0q##S * h0f, rh1 = r0q##S * h1f;               \
    float u0 = v0##S + pm1;                                           \
    float u1 = (v0##S + v1##S) + pm1 * msk##S;                        \
    const int start_ = LS - 2 * (T - (T_));                           \
    if (s0 < start_) u0 = 0.f;                                        \
    if (s1 < start_) u1 = 0.f;                                        \
    const float x0 = u0 * rh0, x1 = u1 * rh1;                         \
    float n0 = x0 * pbv##S[(K_)];                                     \
    float n1 = x1 * plv##S[(K_)];                                     \
    float ssn = wave_sum(n0 + n1);                                    \
    float rn = FQ * fast_rcp(fmaxf(ssn, SEPS) * r1q##S * r2q##S);     \
    rn = fminf(fmaxf(rn, 1e-20f), 1e20f);                             \
    r0q##S = r1q##S; r1q##S = r2q##S; r2q##S = rn;                    \
    v0##S = n0; v1##S = n1;                                           \
    fs##S[(K_)] = ssn;                                                \
    if (!(BETA)) { f0##S[(K_)] = x0; f1##S[(K_)] = x1; }              \
    else { f0##S[(K_)] = n0; }                                        \
  }

  // Publish 8 rows of both chains (normalized, packed). Rows >= T/2 are never
  // read -> skipped. act-guard: lanes 41..63 must not clobber column 40/0.
#define CTC_PUB(T0_)                                                  \
  {                                                                   \
    f1B[7] = wave_shr1(v1B);                                          \
    if (act && (T0_)*2 < T) {                                         \
      _Pragma("unroll")                                               \
      for (int k = 0; k < 8; ++k) {                                   \
        float invA_ = fast_rcp(fmaxf(fsA[k], SEPS));                  \
        sA[((T0_) + k) * PAIRS + colA] =                              \
            packu(f0A[k] * invA_, f1A[k] * invA_);                    \
        float invB_ = fast_rcp(fmaxf(fsB[k], SEPS));                  \
        sB[((T0_) + k) * PAIRS + colB] =                              \
            packu(f0B[k] * invB_, f1B[k] * invB_);                    \
      }                                                               \
    }                                                                 \
  }

  // Loss terms for this block (all guards wave-uniform).
#define CTC_TERMS(T0_)                                                \
  if ((T0_) + 7 >= kstart) {                                          \
    _Pragma("unroll")                                                 \
    for (int kk = 0; kk < 8; ++kk) {                                  \
      const int k = (T0_) + kk;                                       \
      if (k >= kstart && k < T) {                                     \
        const int cross = T - 1 - k;                                  \
        const float invA = fast_rcp(fmaxf(fsA[kk], SEPS));            \
        const unsigned ub = sB[cross * PAIRS + iw];                   \
        float prA =                                                   \
            (bf_lo(ub) * f0A[kk] + bf_hi(ub) * f1A[kk]) * invA;       \
        float dA = wave_sum(prA);                                     \
        acc += __logf(fmaxf(dA, 1e-37f));                             \
        if (2 * k != T - 1) {                                         \
          const float invB = fast_rcp(fmaxf(fsB[kk], SEPS));          \
          const unsigned ua = sA[cross * PAIRS + colB];               \
          float prB =                                                 \
              (bf_lo(ua) * f0B[kk] + bf_hi(ua) * f1B[kk]) * invB;     \
          float dB = wave_sum(prB);                                   \
          acc += __logf(fmaxf(dB, 1e-37f));                           \
        }                                                             \
      }                                                               \
    }                                                                 \
  }

  // ---- prologue: steps 1..7, publish rows 0..7 (no terms: kstart >= 64) ----
#pragma unroll
  for (int k = 1; k < 8; ++k) {
    CTC_STEP(A, 0, k, k);
    CTC_STEP(B, 1, k, k);
  }
  CTC_PUB(0);

  // ---- main: blocks of 8 steps ----
  for (int t0 = 8; t0 < T; t0 += 8) {
    pbvA[0] = LAA.x; pbvA[1] = LAA.y; pbvA[2] = LAA.z; pbvA[3] = LAA.w;
    pbvA[4] = LBA.x; pbvA[5] = LBA.y; pbvA[6] = LBA.z; pbvA[7] = LBA.w;
    plvA[0] = MAA.x; plvA[1] = MAA.y; plvA[2] = MAA.z; plvA[3] = MAA.w;
    plvA[4] = MBA.x; plvA[5] = MBA.y; plvA[6] = MBA.z; plvA[7] = MBA.w;
    pbvB[0] = LAB.x; pbvB[1] = LAB.y; pbvB[2] = LAB.z; pbvB[3] = LAB.w;
    pbvB[4] = LBB.x; pbvB[5] = LBB.y; pbvB[6] = LBB.z; pbvB[7] = LBB.w;
    plvB[0] = MAB.x; plvB[1] = MAB.y; plvB[2] = MAB.z; plvB[3] = MAB.w;
    plvB[4] = MBB.x; plvB[5] = MBB.y; plvB[6] = MBB.z; plvB[7] = MBB.w;
    int np = t0 + 8;
    if (np > 248) np = 248;
    LAA = *(const float4*)(pBA + np); LBA = *(const float4*)(pBA + np + 4);
    MAA = *(const float4*)(pLA + np); MBA = *(const float4*)(pLA + np + 4);
    LAB = *(const float4*)(pBB + np); LBB = *(const float4*)(pBB + np + 4);
    MAB = *(const float4*)(pLB + np); MBB = *(const float4*)(pLB + np + 4);
#pragma unroll
    for (int k = 0; k < 8; ++k) {
      CTC_STEP(A, 0, t0 + k, k);
      CTC_STEP(B, 1, t0 + k, k);
    }
    CTC_PUB(t0);
    CTC_TERMS(t0);
  }
#undef CTC_STEP
#undef CTC_PUB
#undef CTC_TERMS

  if (i == 0) {
    float L = -acc;
    loss_out[b] = fminf(fmaxf(L, -1e30f), 1e30f);  // fmin/fmax absorb NaN
  }
}

__global__ void reduce_kernel(const float* __restrict__ loss_in,
                              float* __restrict__ out) {
  __shared__ double sm[256];
  const int tid = threadIdx.x;
  double s = 0.0;
  for (int k = tid; k < BN; k += 256) s += (double)loss_in[k];
  sm[tid] = s;
  __syncthreads();
  for (int w = 128; w >= 1; w >>= 1) {
    if (tid < w) sm[tid] += sm[tid + w];
    __syncthreads();
  }
  if (tid == 0) out[0] = (float)sm[0];
}
}  // namespace

extern "C" void kernel_launch(void* const* d_in, const int* in_sizes, int n_in,
                              void* d_out, int out_size, void* d_ws, size_t ws_size,
                              hipStream_t stream) {
  const float* gout = (const float*)d_in[0];
  const int* glabel = (const int*)d_in[1];
  const int* gw = (const int*)d_in[2];
  float* loss = (float*)d_ws;  // BN floats (4 KB)
  ctc_fused_kernel<<<BN, 64, 0, stream>>>(gout, glabel, gw, loss);
  reduce_kernel<<<1, 256, 0, stream>>>(loss, (float*)d_out);
}

// Round 3
// 206.694 us; speedup vs baseline: 1.2145x; 1.2145x over previous
//
#include <hip/hip_runtime.h>
#include <cmath>

namespace {
constexpr int BN = 1024;
constexpr int NC = 96;
constexpr int MT = 256;
constexpr int UL = 40;
constexpr int LS = 81;     // 2*UL+1 states
constexpr int PAIRS = 41;  // pairs per row (lane i -> states 2i, 2i+1)

template <int CTRL>
__device__ __forceinline__ float dppf(float v) {
  return __builtin_bit_cast(
      float, __builtin_amdgcn_update_dpp(0, __builtin_bit_cast(int, v), CTRL,
                                         0xf, 0xf, true));
}
__device__ __forceinline__ float rl63(float x) {
  return __builtin_bit_cast(
      float, __builtin_amdgcn_readlane(__builtin_bit_cast(int, x), 63));
}
__device__ __forceinline__ float wave_sum(float x) {
  x += dppf<0x111>(x);
  x += dppf<0x112>(x);
  x += dppf<0x114>(x);
  x += dppf<0x118>(x);
  x += dppf<0x142>(x);
  x += dppf<0x143>(x);
  return rl63(x);
}
// lane i <- lane i-1 (lane 0 <- 0)
__device__ __forceinline__ float wave_shr1(float v) { return dppf<0x138>(v); }
__device__ __forceinline__ float fast_rcp(float x) {
  return __builtin_amdgcn_rcpf(x);
}
__device__ __forceinline__ unsigned packu(float a, float b) {
  unsigned ua = __builtin_bit_cast(unsigned, a) >> 16;
  unsigned ub = __builtin_bit_cast(unsigned, b) & 0xffff0000u;
  return ua | ub;
}
__device__ __forceinline__ float bf_lo(unsigned u) {
  return __builtin_bit_cast(float, u << 16);
}
__device__ __forceinline__ float bf_hi(unsigned u) {
  return __builtin_bit_cast(float, u & 0xffff0000u);
}

constexpr float FQ = 1e8f;      // block-start row scale
constexpr float SEPS = 1e-30f;  // rcp-input floor (NaN-proof)

// One wave per (item, phase). Lane i owns states s=2i, 2i+1.
// DEFERRED-SUM scheme: the 8-step inner loop carries NO wave_sum / rcp —
// the cross-step dependency is just shr1 -> add/fma -> 2 mul. Per-lane row
// totals n0+n1 are saved to sv[k]; at block end 8 INDEPENDENT wave-sums run
// breadth-first (8-way DPP ILP), rows are normalized by their own raw sum at
// pack time (scale-free), and v is rescaled ONCE per block to sum FQ.
// Drift over 8 un-rescaled steps is bounded (min softmax prob >~1e-5, 3-tap
// <=3x): [1e-36, 6.6e3]x of FQ=1e8 — comfortably inside fp32.
// The start_-mask is active only for t > T-41, so the main loop splits into
// an unmasked fast path and a masked tail. Outputs TRANSPOSED [pair][t]
// (bf16x2), combine/reduce unchanged from the verified baseline.
__global__ __launch_bounds__(64) void chain_kernel(
    const float* __restrict__ gout, const int* __restrict__ glabel,
    const int* __restrict__ gw, unsigned* __restrict__ xa,
    unsigned* __restrict__ xb) {
  const int bx = blockIdx.x;
  const int b = bx >> 1, ph = bx & 1;
  const int i = threadIdx.x;
  const float* P = gout + (size_t)b * (NC * MT);  // P[c*MT + t]
  const int* lab = glabel + b * UL;
  const int T = gw[b] >> 2;  // [128,256]

  const int s0 = 2 * i, s1 = s0 + 1;
  const float h0f = (i <= 40) ? 1.f : 0.f;
  const float h1f = (i <= 39) ? 1.f : 0.f;
  const int iw = (i <= 40) ? i : 40;
  const bool act = (i <= 40);

  const float* pB;
  const float* pL;
  float mskf;
  unsigned* outp;
  if (ph == 0) {  // alpha
    const int li = (i < UL) ? lab[i] : 0;
    const int lm = (i >= 1 && i < UL) ? lab[i - 1] : 0;
    pB = P;
    pL = P + (size_t)li * MT;
    mskf = (i >= 1 && i <= 39 && li != lm) ? 1.f : 0.f;
    outp = xa + ((size_t)b * PAIRS + iw) * MT;
  } else {  // beta: class-flipped probs, reversed labels
    const int rli = (i < UL) ? lab[UL - 1 - i] : 0;
    const int rlm = (i >= 1 && i < UL) ? lab[UL - i] : 0;
    pB = P + (size_t)(NC - 1) * MT;
    pL = P + (size_t)(NC - 1 - rli) * MT;
    mskf = (i >= 1 && i <= 39 && rli != rlm) ? 1.f : 0.f;
    outp = xb + ((size_t)b * PAIRS + (40 - iw)) * MT;  // pair-reversed column
  }

  // ---- prob pipeline: current block unpacked, next block in flight ----
  float pbv[8], plv[8];
  float4 LA = *(const float4*)(pB + 0), LB = *(const float4*)(pB + 4);
  float4 MA = *(const float4*)(pL + 0), MB = *(const float4*)(pL + 4);
  pbv[0] = LA.x; pbv[1] = LA.y; pbv[2] = LA.z; pbv[3] = LA.w;
  pbv[4] = LB.x; pbv[5] = LB.y; pbv[6] = LB.z; pbv[7] = LB.w;
  plv[0] = MA.x; plv[1] = MA.y; plv[2] = MA.z; plv[3] = MA.w;
  plv[4] = MB.x; plv[5] = MB.y; plv[6] = MB.z; plv[7] = MB.w;
  LA = *(const float4*)(pB + 8); LB = *(const float4*)(pB + 12);
  MA = *(const float4*)(pL + 8); MB = *(const float4*)(pL + 12);

  // ---- t = 0 ----
  float v0 = (i == 0) ? pbv[0] : 0.f;
  float v1 = (i == 0) ? plv[0] : 0.f;

  float f0[8], f1[8], sv[8];  // 8-step row buffer + per-lane row totals
  if (ph == 0) {
    sv[0] = v0 + v1;               // raw scale matches x=1 convention
    f0[0] = (i == 0) ? 1.f : 0.f;  // x = a_raw/p at t=0
    f1[0] = f0[0];
    v0 *= FQ;
    v1 *= FQ;
  } else {
    v0 *= FQ;
    v1 *= FQ;
    sv[0] = v0 + v1;
    f0[0] = v0;
    f1[0] = 0.f;  // overwritten by step k=1's pm1 (same scale)
  }

#define CTC_STEP(T_, K_, DOMASK)                                      \
  {                                                                   \
    float pm1 = wave_shr1(v1);                                        \
    if (ph == 1 && (K_) >= 1) f1[(K_)-1] = pm1;                       \
    float u0 = v0 + pm1;                                              \
    float u1 = (v0 + v1) + pm1 * mskf;                                \
    if (DOMASK) {                                                     \
      const int start_ = LS - 2 * (T - (T_));                         \
      if (s0 < start_) u0 = 0.f;                                      \
      if (s1 < start_) u1 = 0.f;                                      \
    }                                                                 \
    const float x0 = u0 * h0f, x1 = u1 * h1f;                         \
    float n0 = x0 * pbv[(K_)];                                        \
    float n1 = x1 * plv[(K_)];                                        \
    sv[(K_)] = n0 + n1;                                               \
    v0 = n0; v1 = n1;                                                 \
    if (ph == 0) { f0[(K_)] = x0; f1[(K_)] = x1; }                    \
    else { f0[(K_)] = n0; }                                           \
  }

  // 8 independent wave-sums, breadth-first: 8-way ILP on the DPP trees.
#define WS_LEVEL(CTRL)                                                \
  {                                                                   \
    _Pragma("unroll")                                                 \
    for (int k = 0; k < 8; ++k) sv[k] += dppf<CTRL>(sv[k]);           \
  }

#define CTC_BURST(T0_)                                                \
  {                                                                   \
    if (ph == 1) f1[7] = wave_shr1(v1); /* before rescale! */         \
    WS_LEVEL(0x111) WS_LEVEL(0x112) WS_LEVEL(0x114)                   \
    WS_LEVEL(0x118) WS_LEVEL(0x142) WS_LEVEL(0x143)                   \
    _Pragma("unroll")                                                 \
    for (int k = 0; k < 8; ++k) sv[k] = rl63(sv[k]);                  \
    if (act) {                                                        \
      unsigned ob[8];                                                 \
      _Pragma("unroll")                                               \
      for (int k = 0; k < 8; ++k) {                                   \
        float inv = fast_rcp(fmaxf(sv[k], SEPS));                     \
        ob[k] = packu(f0[k] * inv, f1[k] * inv);                      \
      }                                                               \
      if ((T0_) + 7 < T) {                                            \
        *reinterpret_cast<uint4*>(outp + (T0_)) =                     \
            make_uint4(ob[0], ob[1], ob[2], ob[3]);                   \
        *reinterpret_cast<uint4*>(outp + (T0_) + 4) =                 \
            make_uint4(ob[4], ob[5], ob[6], ob[7]);                   \
      } else {                                                        \
        _Pragma("unroll")                                             \
        for (int k = 0; k < 8; ++k)                                   \
          if ((T0_) + k < T) outp[(T0_) + k] = ob[k];                 \
      }                                                               \
    }                                                                 \
    float rb = FQ * fast_rcp(fmaxf(sv[7], SEPS));                     \
    rb = fminf(fmaxf(rb, 1e-20f), 1e20f);                             \
    v0 *= rb; v1 *= rb;                                               \
  }

#define CTC_UNPACK()                                                  \
  {                                                                   \
    pbv[0] = LA.x; pbv[1] = LA.y; pbv[2] = LA.z; pbv[3] = LA.w;       \
    pbv[4] = LB.x; pbv[5] = LB.y; pbv[6] = LB.z; pbv[7] = LB.w;       \
    plv[0] = MA.x; plv[1] = MA.y; plv[2] = MA.z; plv[3] = MA.w;       \
    plv[4] = MB.x; plv[5] = MB.y; plv[6] = MB.z; plv[7] = MB.w;       \
    int np = t0 + 8;                                                  \
    if (np > 248) np = 248;                                           \
    LA = *(const float4*)(pB + np); LB = *(const float4*)(pB + np + 4); \
    MA = *(const float4*)(pL + np); MB = *(const float4*)(pL + np + 4); \
  }

  // ---- prologue: steps 1..7, rows 0..7 (T>=128 -> unmasked) ----
#pragma unroll
  for (int k = 1; k < 8; ++k) CTC_STEP(k, k, false);
  CTC_BURST(0);

  // ---- main: unmasked fast path (t0+7 <= T-41 -> start_ <= 0) ----
  int t0 = 8;
  for (; t0 + 47 < T; t0 += 8) {
    CTC_UNPACK();
#pragma unroll
    for (int k = 0; k < 8; ++k) CTC_STEP(t0 + k, k, false);
    CTC_BURST(t0);
  }
  // ---- tail: masked blocks ----
  for (; t0 < T; t0 += 8) {
    CTC_UNPACK();
#pragma unroll
    for (int k = 0; k < 8; ++k) CTC_STEP(t0 + k, k, true);
    CTC_BURST(t0);
  }
#undef CTC_STEP
#undef CTC_BURST
#undef CTC_UNPACK
#undef WS_LEVEL
}

// Fully parallel combine: block = item, thread = t. All loads coalesced
// (transposed layout). lh_t = sum_p x'[p][t] * b'[p][T-1-t]; rows are
// pre-normalized at store so no sums arrays are needed.
__global__ __launch_bounds__(256) void combine_kernel(
    const int* __restrict__ gw, const unsigned* __restrict__ xa,
    const unsigned* __restrict__ xb, float* __restrict__ loss_out) {
  const int b = blockIdx.x;
  const int tid = threadIdx.x;
  const int T = gw[b] >> 2;
  float lsum = 0.f;
  if (tid < T) {
    const unsigned* A = xa + (size_t)b * PAIRS * MT + tid;
    const unsigned* Bb = xb + (size_t)b * PAIRS * MT + (T - 1 - tid);
    float d = 0.f;
#pragma unroll
    for (int p = 0; p < PAIRS; ++p) {
      const unsigned av = A[p * MT];
      const unsigned bv = Bb[p * MT];
      d = fmaf(bf_lo(av), bf_lo(bv), d);
      d = fmaf(bf_hi(av), bf_hi(bv), d);
    }
    lsum = -__logf(fmaxf(d, 1e-37f));
  }
  lsum = wave_sum(lsum);
  __shared__ float part[4];
  if ((tid & 63) == 0) part[tid >> 6] = lsum;
  __syncthreads();
  if (tid == 0) {
    float L = part[0] + part[1] + part[2] + part[3];
    loss_out[b] = fminf(fmaxf(L, -1e30f), 1e30f);  // fmin/fmax absorb NaN
  }
}

__global__ void reduce_kernel(const float* __restrict__ loss_in,
                              float* __restrict__ out) {
  __shared__ double sm[256];
  const int tid = threadIdx.x;
  double s = 0.0;
  for (int k = tid; k < BN; k += 256) s += (double)loss_in[k];
  sm[tid] = s;
  __syncthreads();
  for (int w = 128; w >= 1; w >>= 1) {
    if (tid < w) sm[tid] += sm[tid + w];
    __syncthreads();
  }
  if (tid == 0) out[0] = (float)sm[0];
}
}  // namespace

extern "C" void kernel_launch(void* const* d_in, const int* in_sizes, int n_in,
                              void* d_out, int out_size, void* d_ws, size_t ws_size,
                              hipStream_t stream) {
  const float* gout = (const float*)d_in[0];
  const int* glabel = (const int*)d_in[1];
  const int* gw = (const int*)d_in[2];
  unsigned* xa = (unsigned*)d_ws;                  // BN*PAIRS*MT uints (43 MB)
  unsigned* xb = xa + (size_t)BN * PAIRS * MT;     // 43 MB
  float* loss = (float*)(xb + (size_t)BN * PAIRS * MT);  // 4 KB
  chain_kernel<<<2 * BN, 64, 0, stream>>>(gout, glabel, gw, xa, xb);
  combine_kernel<<<BN, 256, 0, stream>>>(gw, xa, xb, loss);
  reduce_kernel<<<1, 256, 0, stream>>>(loss, (float*)d_out);
}